// Round 1
// baseline (1834.826 us; speedup 1.0000x reference)
//
#include <hip/hip_runtime.h>

#define Bn 32
#define Cn 256
#define Hn 224
#define Wn 224
#define COn 256
#define COPB 4                 // out-channels per block

// Fused deformable-sample + 3x3 conv.
// Grid: (Bn * COn/COPB) blocks of 256 threads; thread t == input channel c.
// Phase 1: stage w[co0..co0+3] (9216 floats) into LDS via coalesced float4.
// Phase 2: each thread bilinear-samples its channel's 9 deformable points
//          (registers only -- the old `sh` global round-trip is gone; the
//          redundant reads across co-groups of the same b are L2 hits).
// Phase 3: per co in the group: 49 valid-tap FMAs per thread, 64-lane
//          shfl reduce, 4-wave LDS combine. Identical FP order to the
//          previously verified two-kernel version.
__global__ __launch_bounds__(256) void deform_fused_kernel(
    const float* __restrict__ x, const float* __restrict__ offsets,
    const float* __restrict__ w, const float* __restrict__ bias,
    float* __restrict__ out)
{
    const int nCoG = COn / COPB;           // 64
    int b   = blockIdx.x / nCoG;
    int cog = blockIdx.x - b * nCoG;
    int co0 = cog * COPB;
    int t   = threadIdx.x;                 // channel c

    __shared__ float wl[COPB * Cn * 9];    // 36864 B
    __shared__ float partial[COPB][4][9];

    // ---- Phase 1: weight stage (coalesced float4; 4 co rows are contiguous)
    {
        const float4* wsrc = (const float4*)(w + (size_t)co0 * Cn * 9);
        float4*       wdst = (float4*)wl;
        #pragma unroll
        for (int k = 0; k < (COPB * Cn * 9) / 4 / 256; ++k)   // 9 iters
            wdst[k * 256 + t] = wsrc[k * 256 + t];
    }

    // ---- Phase 2: bilinear sampling, 9 points for this thread's channel
    float v[9];
    const float* plane = x + (size_t)(b * Cn + t) * (Hn * Wn);
    #pragma unroll
    for (int rs = 0; rs < 9; ++rs) {
        int i = rs / 3, j = rs - i * 3;
        // grid[...,0] = gx = (i + off[rs][0]) / (H-1); gx is the WIDTH coord
        float gx = ((float)i + offsets[rs * 2 + 0]) / 223.0f;
        float gy = ((float)j + offsets[rs * 2 + 1]) / 223.0f;
        // align_corners=False unnormalization
        float ix = ((gx + 1.0f) * 224.0f - 1.0f) * 0.5f;
        float iy = ((gy + 1.0f) * 224.0f - 1.0f) * 0.5f;
        float x0f = floorf(ix), y0f = floorf(iy);
        float wx1 = ix - x0f, wx0 = 1.0f - wx1;
        float wy1 = iy - y0f, wy0 = 1.0f - wy1;
        int x0 = (int)x0f, y0 = (int)y0f;
        int x1 = x0 + 1,   y1 = y0 + 1;
        bool vx0 = (x0 >= 0) & (x0 < Wn), vx1 = (x1 >= 0) & (x1 < Wn);
        bool vy0 = (y0 >= 0) & (y0 < Hn), vy1 = (y1 >= 0) & (y1 < Hn);
        float v00 = (vx0 & vy0) ? plane[y0 * Wn + x0] : 0.0f;
        float v10 = (vx1 & vy0) ? plane[y0 * Wn + x1] : 0.0f;
        float v01 = (vx0 & vy1) ? plane[y1 * Wn + x0] : 0.0f;
        float v11 = (vx1 & vy1) ? plane[y1 * Wn + x1] : 0.0f;
        v[rs] = v00 * (wx0 * wy0) + v10 * (wx1 * wy0)
              + v01 * (wx0 * wy1) + v11 * (wx1 * wy1);
    }
    __syncthreads();   // weights staged; samples in registers

    // ---- Phase 3: conv + reduce, one co at a time
    int lane = t & 63, wv = t >> 6;
    #pragma unroll
    for (int g = 0; g < COPB; ++g) {
        const float* wt = &wl[(g * Cn + t) * 9];  // stride 9 -> 2 lanes/bank (free)
        float acc[9];
        #pragma unroll
        for (int k = 0; k < 9; ++k) acc[k] = 0.0f;

        #pragma unroll
        for (int r = 0; r < 3; ++r) {
            #pragma unroll
            for (int s = 0; s < 3; ++s) {
                float vv = v[r * 3 + s];
                #pragma unroll
                for (int p = 0; p < 3; ++p) {
                    if (p < r - 1 || p > r + 1) continue;     // tap row valid
                    #pragma unroll
                    for (int q = 0; q < 3; ++q) {
                        if (q < s - 1 || q > s + 1) continue; // tap col valid
                        acc[p * 3 + q] += vv * wt[(r - p + 1) * 3 + (s - q + 1)];
                    }
                }
            }
        }

        #pragma unroll
        for (int k = 0; k < 9; ++k) {
            float vv = acc[k];
            #pragma unroll
            for (int off = 32; off > 0; off >>= 1)
                vv += __shfl_down(vv, off, 64);
            if (lane == 0) partial[g][wv][k] = vv;
        }
    }
    __syncthreads();

    if (t < COPB * 9) {
        int g = t / 9, k = t - g * 9;
        int co = co0 + g;
        float s = partial[g][0][k] + partial[g][1][k]
                + partial[g][2][k] + partial[g][3][k] + bias[co];
        out[(size_t)(b * COn + co) * 9 + k] = s;
    }
}

extern "C" void kernel_launch(void* const* d_in, const int* in_sizes, int n_in,
                              void* d_out, int out_size, void* d_ws, size_t ws_size,
                              hipStream_t stream) {
    const float* x       = (const float*)d_in[0];
    const float* offsets = (const float*)d_in[1];
    const float* conv_w  = (const float*)d_in[2];
    const float* conv_b  = (const float*)d_in[3];
    float* out = (float*)d_out;

    deform_fused_kernel<<<Bn * (COn / COPB), 256, 0, stream>>>(
        x, offsets, conv_w, conv_b, out);
}